// Round 1
// 11470.417 us; speedup vs baseline: 2.4234x; 2.4234x over previous
//
#include <hip/hip_runtime.h>
#include <stdint.h>

typedef __attribute__((ext_vector_type(8))) short short8;
typedef __attribute__((ext_vector_type(4))) float floatx4;
typedef unsigned short ushort_t;

#define NB 256
#define NT 512
constexpr int B_ = 64, T_ = 512, D_ = 1024, H_ = 1024, O_ = 256;

// ---- ws layout (bytes) ----
constexpr size_t WS_SLOTS = 0;      // unsigned slots[4][64]
constexpr size_t WS_MODE  = 4096;   // unsigned: 1 = f32 inputs
constexpr size_t WS_HBUF  = 8192;   // bf16 hbuf[4][4][64][1024] = 2 MiB
constexpr size_t WS_NEED  = WS_HBUF + (size_t)4*4*B_*H_*2;

constexpr int LDS_BYTES = 131072;   // A-stage [64][1024] bf16; xch overlays first 36864 B

__device__ __forceinline__ float bs2f(ushort_t s){
  union { unsigned u; float f; } v; v.u = ((unsigned)s) << 16; return v.f;
}
__device__ __forceinline__ ushort_t f2bs(float f){
  union { float f; unsigned u; } v; v.f = f;
  unsigned r = (v.u + 0x7fffu + ((v.u >> 16) & 1u)) >> 16;
  return (ushort_t)r;
}
__device__ __forceinline__ float sigf(float x){ return 1.f/(1.f + __expf(-x)); }
__device__ __forceinline__ float tanh_f(float x){ return 1.f - 2.f/(__expf(2.f*x) + 1.f); }
__device__ __forceinline__ short8 ldb8(const ushort_t* p){ return *(const short8*)p; }
__device__ __forceinline__ short8 cvt8v(const float* p){
  floatx4 a = *(const floatx4*)p;
  floatx4 b = *(const floatx4*)(p + 4);
  short8 r;
  #pragma unroll
  for (int j = 0; j < 4; ++j){ r[j] = (short)f2bs(a[j]); r[j+4] = (short)f2bs(b[j]); }
  return r;
}

// system-scope (sc0 sc1) primitives: coherent across XCDs with NO buffer_inv/wbl2.
__device__ __forceinline__ void waitge_sys(unsigned* p, int tgt){
  while ((int)__hip_atomic_load(p, __ATOMIC_RELAXED, __HIP_MEMORY_SCOPE_SYSTEM) < tgt)
    __builtin_amdgcn_s_sleep(2);
  asm volatile("" ::: "memory");   // compiler fence: nothing hoists above the poll
}
__device__ __forceinline__ void st_dword_sys(void* p, unsigned v){
  asm volatile("global_store_dword %0, %1, off sc0 sc1"
               :: "v"((uintptr_t)p), "v"(v) : "memory");
}
// global -> LDS direct DMA, 16B/lane, cpol in AUX (0x11 = sc0|sc1 -> bypass L1/L2)
template<int AUX>
__device__ __forceinline__ void gl2lds16(const void* g, void* l){
  __builtin_amdgcn_global_load_lds(
      (const __attribute__((address_space(1))) unsigned*)g,
      (__attribute__((address_space(3))) unsigned*)l, 16, 0, AUX);
}

// ---- kernel 1: dtype sniff + slot init (runs every launch; resets flags) ----
__global__ void sniff_init(const ushort_t* __restrict__ fcb_u,
                           unsigned* __restrict__ slots, unsigned* __restrict__ mode){
  __shared__ int cnt;
  if (threadIdx.x == 0) cnt = 0;
  __syncthreads();
  slots[threadIdx.x] = 0u;
  unsigned u = fcb_u[threadIdx.x];
  unsigned e = (u >> 7) & 0xFFu;
  if (e >= 0x89u) atomicAdd(&cnt, 1);
  __syncthreads();
  if (threadIdx.x == 0) *mode = (cnt >= 4) ? 1u : 0u;
}

// ---- kernel 2: persistent pipelined LSTM ----
// 256 blocks x 512 thr; block = (layer = bx>>6, 16 h-cols). 8 waves = (gate wg, K-half kh).
// Weights resident in (A)GPRs. A operand staged ONCE per block into LDS per GEMM via
// global_load_lds sc0sc1 (linear LDS, pre-swizzled global source, c ^= r&7 on 16B chunks).
// Sync: per-(layer,slice) flags; sc0sc1 write-through h + vmcnt(0) + relaxed-system flag.
__global__ __launch_bounds__(NT, 2)
void lstm_pipe(const void* __restrict__ xv,   const void* __restrict__ Wihv,
               const void* __restrict__ Whhv, const void* __restrict__ bihv,
               const void* __restrict__ bhhv, const void* __restrict__ fcwv,
               const void* __restrict__ fcbv, void* __restrict__ outv,
               ushort_t* __restrict__ hbuf, unsigned* __restrict__ slots,
               const unsigned* __restrict__ modep)
{
  extern __shared__ char lds_raw[];
  const int tid  = threadIdx.x;
  const int bx   = blockIdx.x;
  const int lane = tid & 63;
  const int wv   = tid >> 6;
  const int q    = lane >> 4;
  const int l15  = lane & 15;
  const int wg   = wv >> 1;           // gate 0..3
  const int kh   = wv & 1;            // K-half
  const int s7   = l15 & 7;           // LDS swizzle key (row low bits; same for all 4 m-tiles)
  const int layer = bx >> 6;
  const int slice = bx & 63;
  const int jbase = slice * 16;

  const unsigned md = *modep;
  const bool f32in  = (md == 1u);
  const float*    xF = (const float*)xv;
  const ushort_t* xB = (const ushort_t*)xv;

  // ---- weight B-fragments into registers (once) ----
  short8 wih_r[16], whh_r[16];
  {
    const size_t wrow = (size_t)layer*4*H_ + (size_t)wg*H_ + jbase + l15;
    const size_t koff = (size_t)kh*512 + q*8;
    if (f32in){
      const float* wi = (const float*)Wihv + wrow*D_ + koff;
      const float* wh = (const float*)Whhv + wrow*H_ + koff;
      #pragma unroll
      for (int kk = 0; kk < 16; ++kk){
        wih_r[kk] = cvt8v(wi + kk*32);
        whh_r[kk] = cvt8v(wh + kk*32);
      }
    } else {
      const ushort_t* wi = (const ushort_t*)Wihv + wrow*D_ + koff;
      const ushort_t* wh = (const ushort_t*)Whhv + wrow*H_ + koff;
      #pragma unroll
      for (int kk = 0; kk < 16; ++kk){
        wih_r[kk] = ldb8(wi + kk*32);
        whh_r[kk] = ldb8(wh + kk*32);
      }
    }
  }

  // ---- pointwise mapping: thread owns (b = tid>>3, col pair j = 2*(tid&7)+{0,1}) ----
  const int pb = tid >> 3;
  const int pj = tid & 7;
  float bsum[4][2];
  {
    #pragma unroll
    for (int g = 0; g < 4; ++g){
      const size_t idx = (size_t)layer*4*H_ + (size_t)g*H_ + jbase + 2*pj;
      if (f32in){
        bsum[g][0] = ((const float*)bihv)[idx]   + ((const float*)bhhv)[idx];
        bsum[g][1] = ((const float*)bihv)[idx+1] + ((const float*)bhhv)[idx+1];
      } else {
        bsum[g][0] = bs2f(((const ushort_t*)bihv)[idx])   + bs2f(((const ushort_t*)bhhv)[idx]);
        bsum[g][1] = bs2f(((const ushort_t*)bihv)[idx+1]) + bs2f(((const ushort_t*)bhhv)[idx+1]);
      }
    }
  }
  float c2[2] = {0.f, 0.f};

  #define GEMM_STEP(WREG) do {                                                 \
    const short8* Ap_ = (const short8*)lds_raw;                                \
    _Pragma("unroll")                                                          \
    for (int kk = 0; kk < 16; ++kk){                                           \
      const int csw = ((kh<<6) + q + (kk<<2)) ^ s7;                            \
      short8 a0 = Ap_[(size_t)(l15+ 0)*128 + csw];                             \
      short8 a1 = Ap_[(size_t)(l15+16)*128 + csw];                             \
      short8 a2 = Ap_[(size_t)(l15+32)*128 + csw];                             \
      short8 a3 = Ap_[(size_t)(l15+48)*128 + csw];                             \
      acc[0] = __builtin_amdgcn_mfma_f32_16x16x32_bf16(a0, WREG[kk], acc[0], 0,0,0); \
      acc[1] = __builtin_amdgcn_mfma_f32_16x16x32_bf16(a1, WREG[kk], acc[1], 0,0,0); \
      acc[2] = __builtin_amdgcn_mfma_f32_16x16x32_bf16(a2, WREG[kk], acc[2], 0,0,0); \
      acc[3] = __builtin_amdgcn_mfma_f32_16x16x32_bf16(a3, WREG[kk], acc[3], 0,0,0); \
    }                                                                          \
  } while(0)

  for (int t = 0; t < T_; ++t){
    // top waits: own-layer h_{t-1} ready (wave 0) + ring back-pressure (wave 1)
    if (t > 0 && tid < 64)                    waitge_sys(&slots[layer*64 + tid], t + 1);
    if (layer < 3 && t >= 3 && tid >= 64 && tid < 128)
                                              waitge_sys(&slots[(layer+1)*64 + (tid-64)], t - 2);
    __syncthreads();                                                   // B1

    floatx4 acc[4];
    #pragma unroll
    for (int mt = 0; mt < 4; ++mt) acc[mt] = floatx4{0.f,0.f,0.f,0.f};

    // R) recurrent GEMM first: stage own h_{t-1} (slot (t-1)&3) -> LDS, then MFMA
    if (t > 0){
      const char* src = (const char*)(hbuf + ((size_t)layer*4 + ((t+3)&3))*(size_t)(B_*H_));
      #pragma unroll
      for (int it = 0; it < 16; ++it){
        const int d = it*NT + tid;
        const int r = d >> 7, c = d & 127, cc = c ^ (r & 7);
        gl2lds16<0x11>(src + (size_t)r*2048 + (size_t)cc*16, lds_raw + (size_t)d*16);
      }
      asm volatile("s_waitcnt vmcnt(0)" ::: "memory");
      __syncthreads();                                                 // B2
      GEMM_STEP(whh_r);
    }

    // I) input GEMM: wait prev layer (overlapped behind recurrent GEMM), restage LDS
    if (layer > 0 && tid < 64) waitge_sys(&slots[(layer-1)*64 + tid], t + 2);
    __syncthreads();                                                   // B4 (LDS reuse fence)

    if (layer == 0){
      if (f32in){
        #pragma unroll 4
        for (int it = 0; it < 16; ++it){
          const int d = it*NT + tid;
          const int r = d >> 7, c = d & 127, cc = c ^ (r & 7);
          const float* sp = xF + ((size_t)r*T_ + t)*D_ + (size_t)cc*8;
          floatx4 A0 = *(const floatx4*)sp, A1 = *(const floatx4*)(sp + 4);
          short8 v;
          #pragma unroll
          for (int j2 = 0; j2 < 4; ++j2){ v[j2] = (short)f2bs(A0[j2]); v[j2+4] = (short)f2bs(A1[j2]); }
          *(short8*)(lds_raw + (size_t)d*16) = v;
        }
      } else {
        const char* srcx = (const char*)xB;
        #pragma unroll
        for (int it = 0; it < 16; ++it){
          const int d = it*NT + tid;
          const int r = d >> 7, c = d & 127, cc = c ^ (r & 7);
          gl2lds16<0>(srcx + (((size_t)r*T_ + t)*D_ + (size_t)cc*8)*2, lds_raw + (size_t)d*16);
        }
      }
    } else {
      const char* srch = (const char*)(hbuf + ((size_t)(layer-1)*4 + (t&3))*(size_t)(B_*H_));
      #pragma unroll
      for (int it = 0; it < 16; ++it){
        const int d = it*NT + tid;
        const int r = d >> 7, c = d & 127, cc = c ^ (r & 7);
        gl2lds16<0x11>(srch + (size_t)r*2048 + (size_t)cc*16, lds_raw + (size_t)d*16);
      }
    }
    asm volatile("s_waitcnt vmcnt(0)" ::: "memory");
    __syncthreads();                                                   // B5
    GEMM_STEP(wih_r);
    __syncthreads();                                                   // B6 (xch overlays LDS)

    // E) exchange partial gates (C/D layout: col=lane&15, row=q*4+r)
    {
      float* xch = (float*)lds_raw;                                    // [4][2][64][18] f32
      #pragma unroll
      for (int mt = 0; mt < 4; ++mt)
        #pragma unroll
        for (int r = 0; r < 4; ++r)
          xch[((size_t)(wg*2 + kh)*64 + mt*16 + q*4 + r)*18 + l15] = acc[mt][r];
    }
    __syncthreads();                                                   // B7

    // F) pointwise cell; pack 2 bf16 -> one sc0sc1 dword store
    {
      const float* xch = (const float*)lds_raw;
      float hv[2];
      #pragma unroll
      for (int u = 0; u < 2; ++u){
        const int j = 2*pj + u;
        #define XG(g) (xch[((size_t)((g)*2+0)*64 + pb)*18 + j] + xch[((size_t)((g)*2+1)*64 + pb)*18 + j])
        float ig = sigf  (XG(0) + bsum[0][u]);
        float fg = sigf  (XG(1) + bsum[1][u]);
        float gg = tanh_f(XG(2) + bsum[2][u]);
        float og = sigf  (XG(3) + bsum[3][u]);
        #undef XG
        float cn = fg*c2[u] + ig*gg;
        c2[u] = cn;
        hv[u] = og*tanh_f(cn);
      }
      unsigned pack = (unsigned)f2bs(hv[0]) | ((unsigned)f2bs(hv[1]) << 16);
      ushort_t* hw = hbuf + ((size_t)layer*4 + (t&3))*(size_t)(B_*H_) + (size_t)pb*H_ + jbase + 2*pj;
      st_dword_sys(hw, pack);
    }
    asm volatile("s_waitcnt vmcnt(0)" ::: "memory");
    __syncthreads();                                                   // B8
    if (tid == 0)
      __hip_atomic_store(&slots[layer*64 + slice], (unsigned)(t + 2),
                         __ATOMIC_RELAXED, __HIP_MEMORY_SCOPE_SYSTEM);
  }

  // ---- FC epilogue: blocks 0..63 -> batch row; LDS-stage final h; threads -> out col ----
  if (bx < B_){
    if (tid < 64) waitge_sys(&slots[3*64 + tid], T_ + 1);
    __syncthreads();
    const char* hr = (const char*)(hbuf + (((size_t)3*4 + ((T_-1)&3))*B_ + bx)*(size_t)H_);
    if (tid < 128) gl2lds16<0x11>(hr + (size_t)tid*16, lds_raw + (size_t)tid*16);
    asm volatile("s_waitcnt vmcnt(0)" ::: "memory");
    __syncthreads();
    if (tid < O_){
      const int b = bx, o = tid;
      const short8* hh = (const short8*)lds_raw;
      if (f32in){
        float acc = ((const float*)fcbv)[o];
        const float* wr = (const float*)fcwv + (size_t)o*H_;
        for (int k8 = 0; k8 < H_/8; ++k8){
          short8 h8 = hh[k8];
          #pragma unroll
          for (int u = 0; u < 8; ++u) acc += bs2f((ushort_t)h8[u]) * wr[k8*8 + u];
        }
        ((float*)outv)[(size_t)b*O_ + o] = acc;
      } else {
        float acc = bs2f(((const ushort_t*)fcbv)[o]);
        const ushort_t* wr = (const ushort_t*)fcwv + (size_t)o*H_;
        for (int k8 = 0; k8 < H_/8; ++k8){
          short8 h8 = hh[k8];
          short8 w8 = ldb8(wr + k8*8);
          #pragma unroll
          for (int u = 0; u < 8; ++u) acc += bs2f((ushort_t)h8[u]) * bs2f((ushort_t)w8[u]);
        }
        ((ushort_t*)outv)[(size_t)b*O_ + o] = f2bs(acc);
      }
    }
  }
  #undef GEMM_STEP
}

extern "C" void kernel_launch(void* const* d_in, const int* in_sizes, int n_in,
                              void* d_out, int out_size, void* d_ws, size_t ws_size,
                              hipStream_t stream){
  static bool attr_done = false;
  if (!attr_done){
    hipFuncSetAttribute(reinterpret_cast<const void*>(&lstm_pipe),
                        hipFuncAttributeMaxDynamicSharedMemorySize, LDS_BYTES);
    attr_done = true;
  }
  char* ws = (char*)d_ws;
  unsigned* slots = (unsigned*)(ws + WS_SLOTS);
  unsigned* mode  = (unsigned*)(ws + WS_MODE);
  ushort_t* hbuf  = (ushort_t*)(ws + WS_HBUF);

  sniff_init<<<1, 256, 0, stream>>>((const ushort_t*)d_in[6], slots, mode);
  lstm_pipe<<<NB, NT, LDS_BYTES, stream>>>(d_in[0], d_in[1], d_in[2], d_in[3], d_in[4],
                                           d_in[5], d_in[6], d_out, hbuf, slots, mode);
}